// Round 4
// baseline (210.652 us; speedup 1.0000x reference)
//
#include <hip/hip_runtime.h>
#include <hip/hip_bf16.h>
#include <math.h>

#define SEQ 4096
#define EMB 1024
#define NH  16
#define DK  64

typedef __attribute__((ext_vector_type(8))) unsigned short us8;
typedef __attribute__((ext_vector_type(8))) short         s8;
typedef __attribute__((ext_vector_type(4))) unsigned short us4;
typedef __attribute__((ext_vector_type(4))) float          f4;

static __device__ __forceinline__ unsigned short f2bf(float f) {
    union { float f; unsigned u; } v; v.f = f;
    unsigned r = v.u + 0x7FFF + ((v.u >> 16) & 1);
    return (unsigned short)(r >> 16);
}

__device__ __forceinline__ void gl2lds16(const void* g, void* l) {
    __builtin_amdgcn_global_load_lds((const __attribute__((address_space(1))) void*)g,
                                     (__attribute__((address_space(3))) void*)l, 16, 0, 0);
}

// pack two fp32 -> one dword of two truncated bf16 (hi = a, lo = b): one v_perm_b32
__device__ __forceinline__ int pkbf(float a, float b) {
    return (int)__builtin_amdgcn_perm(__float_as_uint(a), __float_as_uint(b), 0x07060302u);
}

// ---------------- fp32 -> bf16 convert, all 5 tensors in one launch ----------------
__global__ void cvt_all(const float* __restrict__ x,
                        const float* __restrict__ w0, const float* __restrict__ w1,
                        const float* __restrict__ w2, const float* __restrict__ w3,
                        unsigned short* __restrict__ xo,
                        unsigned short* __restrict__ o0, unsigned short* __restrict__ o1,
                        unsigned short* __restrict__ o2, unsigned short* __restrict__ o3) {
    const int idx = blockIdx.x * 256 + threadIdx.x;
    const float* in;
    unsigned short* out;
    int off;
    if (idx < (1 << 20)) { in = x; out = xo; off = idx; }
    else {
        const int t = idx - (1 << 20);
        const int w = t >> 18;
        off = t & ((1 << 18) - 1);
        in  = w == 0 ? w0 : (w == 1 ? w1 : (w == 2 ? w2 : w3));
        out = w == 0 ? o0 : (w == 1 ? o1 : (w == 2 ? o2 : o3));
    }
    const float4 v = ((const float4*)in)[off];
    us4 o;
    o[0] = f2bf(v.x); o[1] = f2bf(v.y); o[2] = f2bf(v.z); o[3] = f2bf(v.w);
    ((us4*)out)[off] = o;
}

// ---------------- bf16 64x64 transpose with k-permuted output columns ----------------
// pos(k): k=a*16+b*4+c -> (a>>1)*32 + b*8 + (a&1)*4 + c  (matches attn PV frag layout)
__global__ __launch_bounds__(256) void transpose_kernel(
    const unsigned short* __restrict__ in, unsigned short* __restrict__ out) {
    __shared__ unsigned short t[64][72];
    const int tid = threadIdx.x;
    const int row = tid >> 2, c = (tid & 3) * 16;
    const int gr = blockIdx.x * 64, gc = blockIdx.y * 64;
    const unsigned short* src = in + (size_t)(gr + row) * EMB + gc + c;
    *(us8*)&t[row][c]     = *(const us8*)src;
    *(us8*)&t[row][c + 8] = *(const us8*)(src + 8);
    __syncthreads();
    us8 o0, o1;
#pragma unroll
    for (int j = 0; j < 8; ++j) { o0[j] = t[c + j][row]; o1[j] = t[c + 8 + j][row]; }
    const int a_   = c >> 4;
    const int base = (a_ >> 1) * 32 + (a_ & 1) * 4;
    us4 g0, g1, g2, g3;
#pragma unroll
    for (int i = 0; i < 4; ++i) { g0[i] = o0[i]; g1[i] = o0[4 + i]; g2[i] = o1[i]; g3[i] = o1[4 + i]; }
    unsigned short* dst = out + (size_t)(gc + row) * SEQ + gr + base;
    *(us4*)dst        = g0;
    *(us4*)(dst + 8)  = g1;
    *(us4*)(dst + 16) = g2;
    *(us4*)(dst + 24) = g3;
}

// ---------------- fused QKV projection GEMM, 128x128 tile ----------------
__global__ __launch_bounds__(256) void qkv_gemm(
    const unsigned short* __restrict__ X,
    const unsigned short* __restrict__ Wq, const unsigned short* __restrict__ Wk,
    const unsigned short* __restrict__ Wv,
    const float* __restrict__ bq, const float* __restrict__ bk, const float* __restrict__ bv,
    unsigned short* __restrict__ Qo, unsigned short* __restrict__ Ko, unsigned short* __restrict__ Vo)
{
    __shared__ unsigned short As[128 * 64];
    __shared__ unsigned short Bs[128 * 64];

    const int region = blockIdx.y >> 3;
    const unsigned short* W   = region == 0 ? Wq : (region == 1 ? Wk : Wv);
    const float*         bias = region == 0 ? bq : (region == 1 ? bk : bv);
    unsigned short*      out  = region == 0 ? Qo : (region == 1 ? Ko : Vo);
    const float scale = region == 0 ? 0.18033688011112042f : 1.0f;   // 0.125 * log2(e)

    const int tid  = threadIdx.x;
    const int wave = tid >> 6;
    const int lane = tid & 63;
    const int quad = lane >> 4;
    const int l16  = lane & 15;
    const int wm   = (wave >> 1) * 64;
    const int wn   = (wave & 1) * 64;
    const int bm   = blockIdx.x * 128;
    const int bn   = (blockIdx.y & 7) * 128;

    f4 acc[4][4];
#pragma unroll
    for (int a = 0; a < 4; ++a)
#pragma unroll
        for (int b = 0; b < 4; ++b) acc[a][b] = (f4){0, 0, 0, 0};

    const int rsub = lane >> 3;
    const int gc   = ((lane & 7) ^ rsub) * 8;
    const int swz  = l16 & 7;

    for (int k0 = 0; k0 < EMB; k0 += 64) {
        __syncthreads();
#pragma unroll
        for (int i = 0; i < 4; ++i) {
            const int cb = i * 4 + wave;
            const int r  = cb * 8 + rsub;
            gl2lds16(X + (size_t)(bm + r) * EMB + k0 + gc, &As[cb * 512]);
            gl2lds16(W + (size_t)(bn + r) * EMB + k0 + gc, &Bs[cb * 512]);
        }
        __syncthreads();
#pragma unroll
        for (int kc = 0; kc < 2; ++kc) {
            s8 af[4], bf[4];
#pragma unroll
            for (int t = 0; t < 4; ++t) {
                const int seg = (kc * 4 + quad) ^ swz;
                af[t] = *(const s8*)&As[(wm + t * 16 + l16) * 64 + seg * 8];
                bf[t] = *(const s8*)&Bs[(wn + t * 16 + l16) * 64 + seg * 8];
            }
#pragma unroll
            for (int tm = 0; tm < 4; ++tm)
#pragma unroll
                for (int tn = 0; tn < 4; ++tn)
                    acc[tm][tn] = __builtin_amdgcn_mfma_f32_16x16x32_bf16(af[tm], bf[tn], acc[tm][tn], 0, 0, 0);
        }
    }

#pragma unroll
    for (int tn = 0; tn < 4; ++tn) {
        const int n = bn + wn + tn * 16 + l16;
        const float bv2 = bias[n];
#pragma unroll
        for (int tm = 0; tm < 4; ++tm)
#pragma unroll
            for (int rr = 0; rr < 4; ++rr) {
                const int m = bm + wm + tm * 16 + quad * 4 + rr;
                out[(size_t)m * EMB + n] = f2bf((acc[tm][tn][rr] + bv2) * scale);
            }
    }
}

// ---------------- output projection GEMM, 128x64 tile, fp32 out ----------------
__global__ __launch_bounds__(256) void gemm_op(
    const unsigned short* __restrict__ A, const unsigned short* __restrict__ B,
    const float* __restrict__ bias, float* __restrict__ C)
{
    __shared__ unsigned short As[128 * 64];
    __shared__ unsigned short Bs[64 * 64];

    const int tid  = threadIdx.x;
    const int wave = tid >> 6;
    const int lane = tid & 63;
    const int quad = lane >> 4;
    const int l16  = lane & 15;
    const int wm   = (wave >> 1) * 64;
    const int wn   = (wave & 1) * 32;
    const int bm   = blockIdx.x * 128;
    const int bn   = blockIdx.y * 64;

    f4 acc[4][2];
#pragma unroll
    for (int a = 0; a < 4; ++a) { acc[a][0] = (f4){0,0,0,0}; acc[a][1] = (f4){0,0,0,0}; }

    const int rsub = lane >> 3;
    const int gc   = ((lane & 7) ^ rsub) * 8;
    const int swz  = l16 & 7;

    for (int k0 = 0; k0 < EMB; k0 += 64) {
        __syncthreads();
#pragma unroll
        for (int i = 0; i < 6; ++i) {
            const int cb = i * 4 + wave;
            if (cb < 16) {
                gl2lds16(A + (size_t)(bm + cb * 8 + rsub) * EMB + k0 + gc, &As[cb * 512]);
            } else {
                const int c2 = cb - 16;
                gl2lds16(B + (size_t)(bn + c2 * 8 + rsub) * EMB + k0 + gc, &Bs[c2 * 512]);
            }
        }
        __syncthreads();
#pragma unroll
        for (int kc = 0; kc < 2; ++kc) {
            const int seg = (kc * 4 + quad) ^ swz;
            s8 af[4], bf[2];
#pragma unroll
            for (int t = 0; t < 4; ++t)
                af[t] = *(const s8*)&As[(wm + t * 16 + l16) * 64 + seg * 8];
#pragma unroll
            for (int t = 0; t < 2; ++t)
                bf[t] = *(const s8*)&Bs[(wn + t * 16 + l16) * 64 + seg * 8];
#pragma unroll
            for (int tm = 0; tm < 4; ++tm)
#pragma unroll
                for (int tn = 0; tn < 2; ++tn)
                    acc[tm][tn] = __builtin_amdgcn_mfma_f32_16x16x32_bf16(af[tm], bf[tn], acc[tm][tn], 0, 0, 0);
        }
    }

#pragma unroll
    for (int tn = 0; tn < 2; ++tn) {
        const int n = bn + wn + tn * 16 + l16;
        const float bv2 = bias[n];
#pragma unroll
        for (int tm = 0; tm < 4; ++tm)
#pragma unroll
            for (int rr = 0; rr < 4; ++rr) {
                const int m = bm + wm + tm * 16 + quad * 4 + rr;
                C[(size_t)m * EMB + n] = acc[tm][tn][rr] + bv2;
            }
    }
}

// ---------------- Flash attention (causal): adjacent-tile pairing, parity waves ------
// Q,K: bf16 [SEQ][EMB] (Q pre-scaled 0.125*log2e). Vt: bf16 [EMB][SEQ], k-permuted cols.
// Block pairs ADJACENT q-tiles {tB=2g, tA=2g+1} (g in [0,32)) -> their j-streams differ
// by one tile, so the parity schedule (8 waves = {tile} x {qh: 32q half} x {j parity})
// keeps ALL waves busy at the 16-read:32-MFMA ratio for the whole loop (util ~98% vs
// 51% for the old {u,63-u} pairing; round-3's two-phase scheme got util but paid +50%
// ds_reads via 16q high-phase waves -> net regression). Load balance moves ACROSS
// blocks: work ~ g+1; blockIdx mapping puts b and b+256 (same XCD, 2 blocks/CU) on
// complementary g and 31-g (33 pair-iterations per CU), and gives each XCD 2 heads
// (K/V prefix shared in L2, ~2MB/XCD). Stream length 2g+2 (always even -> pair staging
// never has a missing odd sub). K,V staged in LDS (XOR-swizzled, gl2lds pre-swizzled
// src, 64KB, 2 blocks/CU). Epilogue: parity merge through dead Ks/Vs, both tiles.
// Fixed-max softmax, exp2 domain, zero-shfl PV, setprio on MFMA clusters (T5).
__global__ __launch_bounds__(512, 4) void attn_kernel(
    const unsigned short* __restrict__ Qg, const unsigned short* __restrict__ Kg,
    const unsigned short* __restrict__ Vtg, unsigned short* __restrict__ Og)
{
    __shared__ unsigned short Ks[2][2][64][64];   // [buf][j&1][row][col^swz]  32KB
    __shared__ unsigned short Vs[2][2][64][64];   //                            32KB

    const int tid  = threadIdx.x;
    const int wave = tid >> 6;
    const int lane = tid & 63;
    const int quad = lane >> 4;
    const int l16  = lane & 15;

    // blockIdx -> (head, g): xcd = b&7 owns heads {2*xcd, 2*xcd+1}; rounds r=0 (g=31-i4,
    // long, dispatched first) and r=1 (g=i4) pair complementary g on the same CU.
    const int b   = blockIdx.x;
    const int xcd = b & 7;
    const int i6  = b >> 3;                         // 0..63
    const int rnd = i6 >> 5;                        // 0 | 1
    const int i5  = i6 & 31;
    const int h   = xcd * 2 + (i5 >> 4);
    const int i4  = i5 & 15;
    const int g   = rnd ? i4 : 31 - i4;             // g in [0,32)
    const int tA  = 2 * g + 1;
    const int tB  = 2 * g;

    const int par  = (wave >> 1) & 1;               // j parity this wave computes
    const int qh   = wave & 1;                      // 32q half
    const bool isA = wave < 4;
    const int tileMine = isA ? tA : tB;
    const int jmine    = tileMine;                  // diagonal j == tile index
    const int colbase  = h * DK;
    const int q0       = tileMine * 64 + qh * 32 + l16;   // qn0 row; qn1 = q0+16

    // Q B-frags [kc][qn]: B[n=q][k=kc*32+quad*8+j]
    s8 qf00, qf10, qf01, qf11;
    {
        const unsigned short* q = Qg + (size_t)q0 * EMB + colbase + quad * 8;
        qf00 = *(const s8*)(q);
        qf10 = *(const s8*)(q + 32);
        qf01 = *(const s8*)(q + (size_t)16 * EMB);
        qf11 = *(const s8*)(q + (size_t)16 * EMB + 32);
    }

    // swizzled LDS read offsets (shorts)
    const int xr    = (l16 & 7) << 4;
    const int coff0 = ((quad * 16) ^ xr) >> 1;
    const int coff1 = ((64 + quad * 16) ^ xr) >> 1;

    // staging: 512 thr, 16B each per 64x64 sub-tile; linear LDS dest, pre-swizzled src
    const int srow = tid >> 3;
    const int scol = (((tid & 7) * 16) ^ ((srow & 7) << 4)) >> 1;
    const unsigned short* ksrc = Kg  + (size_t)srow * EMB + colbase + scol;
    const unsigned short* vsrc = Vtg + (size_t)(colbase + srow) * SEQ + scol;

    // prologue: stage pair 0 (j=0,1; j=1 <= tA always)
    gl2lds16(ksrc,                    &Ks[0][0][wave * 8][0]);
    gl2lds16(vsrc,                    &Vs[0][0][wave * 8][0]);
    gl2lds16(ksrc + (size_t)64 * EMB, &Ks[0][1][wave * 8][0]);
    gl2lds16(vsrc + 64,               &Vs[0][1][wave * 8][0]);

    float l0 = 0.0f, l1 = 0.0f;
    f4 o0[4], o1[4];
#pragma unroll
    for (int t = 0; t < 4; ++t) { o0[t] = (f4){0, 0, 0, 0}; o1[t] = (f4){0, 0, 0, 0}; }

    // ---------------- main loop: pairs i = 0..g, j-stream 0..2g+1 ----------------
    for (int i = 0; i <= g; ++i) {
        __syncthreads();
        const int cur = i & 1;
        if (i < g) {                                // stage pair i+1 (both subs valid)
            const int je = 2 * (i + 1);
            gl2lds16(ksrc + (size_t)je * 64 * EMB,       &Ks[cur ^ 1][0][wave * 8][0]);
            gl2lds16(vsrc + (size_t)je * 64,             &Vs[cur ^ 1][0][wave * 8][0]);
            gl2lds16(ksrc + (size_t)(je + 1) * 64 * EMB, &Ks[cur ^ 1][1][wave * 8][0]);
            gl2lds16(vsrc + (size_t)(je + 1) * 64,       &Vs[cur ^ 1][1][wave * 8][0]);
        }
        const int j = 2 * i + par;
        if (j <= jmine) {                           // only tile-B par1 skips, at i==g
            const unsigned short* KsP = &Ks[cur][par][0][0];
            const unsigned short* VsP = &Vs[cur][par][0][0];

            // S^T[k][q] = K . Q^T, two q-subtiles share each K fragment
            f4 s0[4] = { {0,0,0,0}, {0,0,0,0}, {0,0,0,0}, {0,0,0,0} };
            f4 s1[4] = { {0,0,0,0}, {0,0,0,0}, {0,0,0,0}, {0,0,0,0} };
            __builtin_amdgcn_s_setprio(1);
#pragma unroll
            for (int t = 0; t < 4; ++t) {
                const int rbase = (t * 16 + l16) * 64;
                s8 kv0 = *(const s8*)&KsP[rbase + coff0];
                s8 kv1 = *(const s8*)&KsP[rbase + coff1];
                s0[t] = __builtin_amdgcn_mfma_f32_16x16x32_bf16(kv0, qf00, s0[t], 0, 0, 0);
                s1[t] = __builtin_amdgcn_mfma_f32_16x16x32_bf16(kv0, qf01, s1[t], 0, 0, 0);
                s0[t] = __builtin_amdgcn_mfma_f32_16x16x32_bf16(kv1, qf10, s0[t], 0, 0, 0);
                s1[t] = __builtin_amdgcn_mfma_f32_16x16x32_bf16(kv1, qf11, s1[t], 0, 0, 0);
            }
            __builtin_amdgcn_s_setprio(0);

            if (j == jmine) {                       // diagonal tile: mask k > q
#pragma unroll
                for (int t = 0; t < 4; ++t) {
                    const int kb = j * 64 + t * 16 + quad * 4;
#pragma unroll
                    for (int r = 0; r < 4; ++r) {
                        if (kb + r > q0)      s0[t][r] = -1e30f;
                        if (kb + r > q0 + 16) s1[t][r] = -1e30f;
                    }
                }
            }

            // fixed-max softmax in exp2 domain; column sums in-reg + 2 shfl per qn
            float rs0 = 0.0f, rs1 = 0.0f;
#pragma unroll
            for (int t = 0; t < 4; ++t)
#pragma unroll
                for (int r = 0; r < 4; ++r) {
                    const float p0 = __builtin_amdgcn_exp2f(s0[t][r]);
                    const float p1 = __builtin_amdgcn_exp2f(s1[t][r]);
                    s0[t][r] = p0; rs0 += p0;
                    s1[t][r] = p1; rs1 += p1;
                }
            rs0 += __shfl_xor(rs0, 16);
            rs0 += __shfl_xor(rs0, 32);
            rs1 += __shfl_xor(rs1, 16);
            rs1 += __shfl_xor(rs1, 32);
            l0 += rs0;
            l1 += rs1;

            // pack P pairs (trunc bf16); own regs ARE the PV B-frag (k-permuted)
            union { int i[8]; s8 v[2]; } pk0, pk1;
#pragma unroll
            for (int t = 0; t < 4; ++t) {
                pk0.i[t * 2]     = pkbf(s0[t][1], s0[t][0]);
                pk0.i[t * 2 + 1] = pkbf(s0[t][3], s0[t][2]);
                pk1.i[t * 2]     = pkbf(s1[t][1], s1[t][0]);
                pk1.i[t * 2 + 1] = pkbf(s1[t][3], s1[t][2]);
            }

            // O^T[d][q] += V^T . P, two q-subtiles share each V fragment
            __builtin_amdgcn_s_setprio(1);
#pragma unroll
            for (int t = 0; t < 4; ++t) {
                const int rbase = (t * 16 + l16) * 64;
                s8 va0 = *(const s8*)&VsP[rbase + coff0];
                s8 va1 = *(const s8*)&VsP[rbase + coff1];
                o0[t] = __builtin_amdgcn_mfma_f32_16x16x32_bf16(va0, pk0.v[0], o0[t], 0, 0, 0);
                o1[t] = __builtin_amdgcn_mfma_f32_16x16x32_bf16(va0, pk1.v[0], o1[t], 0, 0, 0);
                o0[t] = __builtin_amdgcn_mfma_f32_16x16x32_bf16(va1, pk0.v[1], o0[t], 0, 0, 0);
                o1[t] = __builtin_amdgcn_mfma_f32_16x16x32_bf16(va1, pk1.v[1], o1[t], 0, 0, 0);
            }
            __builtin_amdgcn_s_setprio(0);
        }
    }

    // ---------------- EPILOGUE: parity merge via dead Ks/Vs, both tiles ----------------
    __syncthreads();                                // all LDS reads + staging quiesced
    float* mO8 = (float*)&Ks[0][0][0][0];           // [8 slots][16 elems][64 lanes] 32KB
    float* mL8 = (float*)&Vs[0][0][0][0];           // [8 slots][64 lanes]            2KB
    const int slot0 = (isA ? 0 : 4) + qh * 2;       // qn0 slot; qn1 = slot0+1
    if (par == 1) {                                 // park partials
#pragma unroll
        for (int t = 0; t < 4; ++t)
#pragma unroll
            for (int r = 0; r < 4; ++r) {
                mO8[(slot0       * 16 + t * 4 + r) * 64 + lane] = o0[t][r];
                mO8[((slot0 + 1) * 16 + t * 4 + r) * 64 + lane] = o1[t][r];
            }
        mL8[slot0 * 64 + lane]       = l0;
        mL8[(slot0 + 1) * 64 + lane] = l1;
    }
    __syncthreads();
    if (par == 0) {                                 // merge + normalize + store 32 rows
        const float inv0 = 1.0f / (l0 + mL8[slot0 * 64 + lane]);
        const float inv1 = 1.0f / (l1 + mL8[(slot0 + 1) * 64 + lane]);
#pragma unroll
        for (int t = 0; t < 4; ++t) {
            us4 ov;
#pragma unroll
            for (int r = 0; r < 4; ++r)
                ov[r] = f2bf((o0[t][r] + mO8[(slot0 * 16 + t * 4 + r) * 64 + lane]) * inv0);
            *(us4*)&Og[(size_t)q0 * EMB + colbase + t * 16 + quad * 4] = ov;
#pragma unroll
            for (int r = 0; r < 4; ++r)
                ov[r] = f2bf((o1[t][r] + mO8[((slot0 + 1) * 16 + t * 4 + r) * 64 + lane]) * inv1);
            *(us4*)&Og[(size_t)(q0 + 16) * EMB + colbase + t * 16 + quad * 4] = ov;
        }
    }
}

extern "C" void kernel_launch(void* const* d_in, const int* in_sizes, int n_in,
                              void* d_out, int out_size, void* d_ws, size_t ws_size,
                              hipStream_t stream) {
    const float* x  = (const float*)d_in[0];
    const float* Wq = (const float*)d_in[1];
    const float* bq = (const float*)d_in[2];
    const float* Wk = (const float*)d_in[3];
    const float* bk = (const float*)d_in[4];
    const float* Wv = (const float*)d_in[5];
    const float* bv = (const float*)d_in[6];
    const float* Wo = (const float*)d_in[7];
    const float* bo = (const float*)d_in[8];
    float* out = (float*)d_out;

    unsigned short* ws = (unsigned short*)d_ws;
    unsigned short* xb  = ws;                          // [4096][1024]
    unsigned short* Wqb = xb  + (size_t)SEQ * EMB;     // [1024][1024] x4
    unsigned short* Wkb = Wqb + (size_t)EMB * EMB;
    unsigned short* Wvb = Wkb + (size_t)EMB * EMB;
    unsigned short* Wob = Wvb + (size_t)EMB * EMB;
    unsigned short* Qb  = Wob + (size_t)EMB * EMB;     // [4096][1024], pre-scaled 0.125*log2e
    unsigned short* Kb  = Qb  + (size_t)SEQ * EMB;     // [4096][1024]
    unsigned short* Vtb = Kb  + (size_t)SEQ * EMB;     // [1024][4096]  V^T, k-permuted cols
    unsigned short* Ab  = Vtb + (size_t)SEQ * EMB;     // V (pre-transpose), then attn out

    cvt_all<<<8192, 256, 0, stream>>>(x, Wq, Wk, Wv, Wo, xb, Wqb, Wkb, Wvb, Wob);

    qkv_gemm<<<dim3(SEQ / 128, 24), 256, 0, stream>>>(xb, Wqb, Wkb, Wvb, bq, bk, bv, Qb, Kb, Ab);

    transpose_kernel<<<dim3(SEQ / 64, EMB / 64), 256, 0, stream>>>(Ab, Vtb);

    attn_kernel<<<512, 512, 0, stream>>>(Qb, Kb, Vtb, Ab);

    gemm_op<<<dim3(SEQ / 128, EMB / 64), 256, 0, stream>>>(Ab, Wob, bo, out);
}

// Round 5
// 198.625 us; speedup vs baseline: 1.0605x; 1.0605x over previous
//
#include <hip/hip_runtime.h>
#include <hip/hip_bf16.h>
#include <math.h>

#define SEQ 4096
#define EMB 1024
#define NH  16
#define DK  64

typedef __attribute__((ext_vector_type(8))) unsigned short us8;
typedef __attribute__((ext_vector_type(8))) short         s8;
typedef __attribute__((ext_vector_type(4))) unsigned short us4;
typedef __attribute__((ext_vector_type(4))) float          f4;

static __device__ __forceinline__ unsigned short f2bf(float f) {
    union { float f; unsigned u; } v; v.f = f;
    unsigned r = v.u + 0x7FFF + ((v.u >> 16) & 1);
    return (unsigned short)(r >> 16);
}

__device__ __forceinline__ void gl2lds16(const void* g, void* l) {
    __builtin_amdgcn_global_load_lds((const __attribute__((address_space(1))) void*)g,
                                     (__attribute__((address_space(3))) void*)l, 16, 0, 0);
}

// pack two fp32 -> one dword of two truncated bf16 (hi = a, lo = b): one v_perm_b32
__device__ __forceinline__ int pkbf(float a, float b) {
    return (int)__builtin_amdgcn_perm(__float_as_uint(a), __float_as_uint(b), 0x07060302u);
}

// ---------------- fp32 -> bf16 convert, all 5 tensors in one launch ----------------
__global__ void cvt_all(const float* __restrict__ x,
                        const float* __restrict__ w0, const float* __restrict__ w1,
                        const float* __restrict__ w2, const float* __restrict__ w3,
                        unsigned short* __restrict__ xo,
                        unsigned short* __restrict__ o0, unsigned short* __restrict__ o1,
                        unsigned short* __restrict__ o2, unsigned short* __restrict__ o3) {
    const int idx = blockIdx.x * 256 + threadIdx.x;
    const float* in;
    unsigned short* out;
    int off;
    if (idx < (1 << 20)) { in = x; out = xo; off = idx; }
    else {
        const int t = idx - (1 << 20);
        const int w = t >> 18;
        off = t & ((1 << 18) - 1);
        in  = w == 0 ? w0 : (w == 1 ? w1 : (w == 2 ? w2 : w3));
        out = w == 0 ? o0 : (w == 1 ? o1 : (w == 2 ? o2 : o3));
    }
    const float4 v = ((const float4*)in)[off];
    us4 o;
    o[0] = f2bf(v.x); o[1] = f2bf(v.y); o[2] = f2bf(v.z); o[3] = f2bf(v.w);
    ((us4*)out)[off] = o;
}

// ---------------- fused QKV projection GEMM, 128x128 tile ----------------
// V region (region==2) writes its output DIRECTLY TRANSPOSED with k-permuted columns
// into Vt [EMB][SEQ] (replaces the separate transpose_kernel: -16MB r/w, -1 launch).
// perm within each 64-row s-block: s = a*16 + b*4 + c -> (a>>1)*32 + b*8 + (a&1)*4 + c;
// in the C-fragment layout b==quad and c==rr, so the 4 rr values stay contiguous (us4).
__global__ __launch_bounds__(256) void qkv_gemm(
    const unsigned short* __restrict__ X,
    const unsigned short* __restrict__ Wq, const unsigned short* __restrict__ Wk,
    const unsigned short* __restrict__ Wv,
    const float* __restrict__ bq, const float* __restrict__ bk, const float* __restrict__ bv,
    unsigned short* __restrict__ Qo, unsigned short* __restrict__ Ko, unsigned short* __restrict__ Vto)
{
    __shared__ unsigned short As[128 * 64];
    __shared__ unsigned short Bs[128 * 64];

    // XCD-bijective swizzle: 768 blocks = 8 XCDs x 96 -> each XCD gets 3 consecutive
    // (region, bn) panels over all M (W panel stays L2-resident per XCD).
    const int flat = blockIdx.y * 32 + blockIdx.x;
    const int wg   = (flat & 7) * 96 + (flat >> 3);
    const int bxi  = wg & 31;
    const int byi  = wg >> 5;

    const int region = byi >> 3;
    const unsigned short* W   = region == 0 ? Wq : (region == 1 ? Wk : Wv);
    const float*         bias = region == 0 ? bq : (region == 1 ? bk : bv);
    const float scale = region == 0 ? 0.18033688011112042f : 1.0f;   // 0.125 * log2(e)

    const int tid  = threadIdx.x;
    const int wave = tid >> 6;
    const int lane = tid & 63;
    const int quad = lane >> 4;
    const int l16  = lane & 15;
    const int wm   = (wave >> 1) * 64;
    const int wn   = (wave & 1) * 64;
    const int bm   = bxi * 128;
    const int bn   = (byi & 7) * 128;

    f4 acc[4][4];
#pragma unroll
    for (int a = 0; a < 4; ++a)
#pragma unroll
        for (int b = 0; b < 4; ++b) acc[a][b] = (f4){0, 0, 0, 0};

    const int rsub = lane >> 3;
    const int gc   = ((lane & 7) ^ rsub) * 8;
    const int swz  = l16 & 7;

    for (int k0 = 0; k0 < EMB; k0 += 64) {
        __syncthreads();
#pragma unroll
        for (int i = 0; i < 4; ++i) {
            const int cb = i * 4 + wave;
            const int r  = cb * 8 + rsub;
            gl2lds16(X + (size_t)(bm + r) * EMB + k0 + gc, &As[cb * 512]);
            gl2lds16(W + (size_t)(bn + r) * EMB + k0 + gc, &Bs[cb * 512]);
        }
        __syncthreads();
#pragma unroll
        for (int kc = 0; kc < 2; ++kc) {
            s8 af[4], bf[4];
#pragma unroll
            for (int t = 0; t < 4; ++t) {
                const int seg = (kc * 4 + quad) ^ swz;
                af[t] = *(const s8*)&As[(wm + t * 16 + l16) * 64 + seg * 8];
                bf[t] = *(const s8*)&Bs[(wn + t * 16 + l16) * 64 + seg * 8];
            }
#pragma unroll
            for (int tm = 0; tm < 4; ++tm)
#pragma unroll
                for (int tn = 0; tn < 4; ++tn)
                    acc[tm][tn] = __builtin_amdgcn_mfma_f32_16x16x32_bf16(af[tm], bf[tn], acc[tm][tn], 0, 0, 0);
        }
    }

    if (region == 2) {
        // transposed + k-permuted store into Vt [EMB][SEQ]
#pragma unroll
        for (int tn = 0; tn < 4; ++tn) {
            const int n = bn + wn + tn * 16 + l16;          // output d-column
            const float bv2 = bias[n];
#pragma unroll
            for (int tm = 0; tm < 4; ++tm) {
                us4 ov;
#pragma unroll
                for (int rr = 0; rr < 4; ++rr) ov[rr] = f2bf(acc[tm][tn][rr] + bv2);
                const int pos = (tm >> 1) * 32 + quad * 8 + (tm & 1) * 4;   // perm base (c=rr contiguous)
                *(us4*)&Vto[(size_t)n * SEQ + bm + (wm & 64) + pos] = ov;
            }
        }
    } else {
#pragma unroll
        for (int tn = 0; tn < 4; ++tn) {
            const int n = bn + wn + tn * 16 + l16;
            const float bv2 = bias[n];
            unsigned short* out = region == 0 ? Qo : Ko;
#pragma unroll
            for (int tm = 0; tm < 4; ++tm)
#pragma unroll
                for (int rr = 0; rr < 4; ++rr) {
                    const int m = bm + wm + tm * 16 + quad * 4 + rr;
                    out[(size_t)m * EMB + n] = f2bf((acc[tm][tn][rr] + bv2) * scale);
                }
        }
    }
}

// ---------------- output projection GEMM, 128x64 tile, fp32 out ----------------
__global__ __launch_bounds__(256) void gemm_op(
    const unsigned short* __restrict__ A, const unsigned short* __restrict__ B,
    const float* __restrict__ bias, float* __restrict__ C)
{
    __shared__ unsigned short As[128 * 64];
    __shared__ unsigned short Bs[64 * 64];

    // XCD-bijective swizzle: 512 blocks = 8 x 64 -> 2 consecutive bn panels per XCD
    const int flat = blockIdx.y * 32 + blockIdx.x;
    const int wg   = (flat & 7) * 64 + (flat >> 3);
    const int bxi  = wg & 31;
    const int byi  = wg >> 5;

    const int tid  = threadIdx.x;
    const int wave = tid >> 6;
    const int lane = tid & 63;
    const int quad = lane >> 4;
    const int l16  = lane & 15;
    const int wm   = (wave >> 1) * 64;
    const int wn   = (wave & 1) * 32;
    const int bm   = bxi * 128;
    const int bn   = byi * 64;

    f4 acc[4][2];
#pragma unroll
    for (int a = 0; a < 4; ++a) { acc[a][0] = (f4){0,0,0,0}; acc[a][1] = (f4){0,0,0,0}; }

    const int rsub = lane >> 3;
    const int gc   = ((lane & 7) ^ rsub) * 8;
    const int swz  = l16 & 7;

    for (int k0 = 0; k0 < EMB; k0 += 64) {
        __syncthreads();
#pragma unroll
        for (int i = 0; i < 6; ++i) {
            const int cb = i * 4 + wave;
            if (cb < 16) {
                gl2lds16(A + (size_t)(bm + cb * 8 + rsub) * EMB + k0 + gc, &As[cb * 512]);
            } else {
                const int c2 = cb - 16;
                gl2lds16(B + (size_t)(bn + c2 * 8 + rsub) * EMB + k0 + gc, &Bs[c2 * 512]);
            }
        }
        __syncthreads();
#pragma unroll
        for (int kc = 0; kc < 2; ++kc) {
            const int seg = (kc * 4 + quad) ^ swz;
            s8 af[4], bf[2];
#pragma unroll
            for (int t = 0; t < 4; ++t)
                af[t] = *(const s8*)&As[(wm + t * 16 + l16) * 64 + seg * 8];
#pragma unroll
            for (int t = 0; t < 2; ++t)
                bf[t] = *(const s8*)&Bs[(wn + t * 16 + l16) * 64 + seg * 8];
#pragma unroll
            for (int tm = 0; tm < 4; ++tm)
#pragma unroll
                for (int tn = 0; tn < 2; ++tn)
                    acc[tm][tn] = __builtin_amdgcn_mfma_f32_16x16x32_bf16(af[tm], bf[tn], acc[tm][tn], 0, 0, 0);
        }
    }

#pragma unroll
    for (int tn = 0; tn < 2; ++tn) {
        const int n = bn + wn + tn * 16 + l16;
        const float bv2 = bias[n];
#pragma unroll
        for (int tm = 0; tm < 4; ++tm)
#pragma unroll
            for (int rr = 0; rr < 4; ++rr) {
                const int m = bm + wm + tm * 16 + quad * 4 + rr;
                C[(size_t)m * EMB + n] = acc[tm][tn][rr] + bv2;
            }
    }
}

// ---------------- Flash attention (causal): parity-split waves, 32q/wave ----------------
// [round-1 kernel, verbatim: measured 53.1us, MfmaUtil 26%, 0-ish conflicts, no spill]
// Q,K: bf16 [SEQ][EMB] (Q pre-scaled 0.125*log2e). Vt: bf16 [EMB][SEQ], k-permuted cols.
// Block = 512 thr / 8 waves, grid (NH,32), u = y<16 ? y : 47-y, tiles {63-u, u} per block.
// Each 64-q tile is covered by 2 waves x 32q (qn=0/1 subtiles); the 2 waves split the
// j-stream by PARITY. One K/V ds_read_b128 feeds 2 MFMAs (shared A-operand across qn).
// LDS tiles unpadded [64][64], m214 XOR swizzle (byte ^= (row&7)<<4), staged by
// global_load_lds with pre-swizzled GLOBAL source (linear LDS dest). Parity partials
// (O, l) merge through LDS at epilogue. Fixed-max softmax, exp2 domain, zero-shfl PV.
__global__ __launch_bounds__(512, 4) void attn_kernel(
    const unsigned short* __restrict__ Qg, const unsigned short* __restrict__ Kg,
    const unsigned short* __restrict__ Vtg, unsigned short* __restrict__ Og)
{
    __shared__ unsigned short Ks[2][2][64][64];   // [buf][parity][row][col^swz]
    __shared__ unsigned short Vs[2][2][64][64];

    const int tid  = threadIdx.x;
    const int wave = tid >> 6;
    const int lane = tid & 63;
    const int quad = lane >> 4;
    const int l16  = lane & 15;
    const int h    = blockIdx.x;
    const int y    = blockIdx.y;
    const int u    = (y < 16) ? y : 47 - y;
    const int jmax = 63 - u;                        // tile-A diagonal, >= 32
    const int tileMine = (wave < 4) ? (63 - u) : u;
    const int par  = (wave >> 1) & 1;               // j parity this wave computes
    const int qh   = wave & 1;                      // which 32-q half of the tile
    const int jmine = tileMine;                     // diagonal j of this wave's tile
    const int colbase = h * DK;
    const int wrow0 = tileMine * 64 + qh * 32;
    const int q0    = wrow0 + l16;                  // qn=0 row; qn=1 row is q0+16

    // Q B-frags [kc][qn]: B[n=q][k=kc*32+quad*8+j]
    s8 qf00, qf10, qf01, qf11;
    {
        const unsigned short* q = Qg + (size_t)q0 * EMB + colbase + quad * 8;
        qf00 = *(const s8*)(q);
        qf10 = *(const s8*)(q + 32);
        qf01 = *(const s8*)(q + (size_t)16 * EMB);
        qf11 = *(const s8*)(q + (size_t)16 * EMB + 32);
    }

    // swizzled LDS read offsets (shorts); xr = (row&7)<<4 byte XOR, row%8 == l16%8
    const int xr    = (l16 & 7) << 4;
    const int coff0 = ((quad * 16) ^ xr) >> 1;          // kc = 0
    const int coff1 = (((64) + quad * 16) ^ xr) >> 1;   // kc = 1

    // staging: 512 thr cover 64 rows x 8 chunks of 16B per [64][64] sub-tile;
    // LDS dest is linear (wave-uniform base + lane*16), global source pre-swizzled
    const int srow = tid >> 3;                      // 0..63
    const int scol = (((tid & 7) * 16) ^ ((srow & 7) << 4)) >> 1;
    const unsigned short* ksrc = Kg  + (size_t)srow * EMB + colbase + scol;
    const unsigned short* vsrc = Vtg + (size_t)(colbase + srow) * SEQ + scol;

    const int imax = jmax >> 1;                     // pair index range 0..imax

    // stage pair 0 (j=0 even, j=1 odd; j=1 exists since jmax >= 32)
    gl2lds16(ksrc,                    &Ks[0][0][wave * 8][0]);
    gl2lds16(vsrc,                    &Vs[0][0][wave * 8][0]);
    gl2lds16(ksrc + (size_t)64 * EMB, &Ks[0][1][wave * 8][0]);
    gl2lds16(vsrc + 64,               &Vs[0][1][wave * 8][0]);

    float l0 = 0.0f, l1 = 0.0f;
    f4 o0[4], o1[4];
#pragma unroll
    for (int t = 0; t < 4; ++t) { o0[t] = (f4){0, 0, 0, 0}; o1[t] = (f4){0, 0, 0, 0}; }

    for (int i = 0; i <= imax; ++i) {
        __syncthreads();                            // pair i staged; buffers safe to swap
        const int cur = i & 1;
        if (i < imax) {                             // issue pair i+1 (async, drained by next barrier)
            const int nxt = cur ^ 1;
            const int je  = 2 * (i + 1);
            gl2lds16(ksrc + (size_t)je * 64 * EMB, &Ks[nxt][0][wave * 8][0]);
            gl2lds16(vsrc + (size_t)je * 64,       &Vs[nxt][0][wave * 8][0]);
            const int jo = je + 1;
            if (jo <= jmax) {                       // block-uniform guard
                gl2lds16(ksrc + (size_t)jo * 64 * EMB, &Ks[nxt][1][wave * 8][0]);
                gl2lds16(vsrc + (size_t)jo * 64,       &Vs[nxt][1][wave * 8][0]);
            }
        }

        const int j = 2 * i + par;
        if (j <= jmine) {
            const unsigned short* KsP = &Ks[cur][par][0][0];
            const unsigned short* VsP = &Vs[cur][par][0][0];

            // S^T[k][q] = K . Q^T, two q-subtiles share each K fragment
            f4 s0[4] = { {0,0,0,0}, {0,0,0,0}, {0,0,0,0}, {0,0,0,0} };
            f4 s1[4] = { {0,0,0,0}, {0,0,0,0}, {0,0,0,0}, {0,0,0,0} };
            __builtin_amdgcn_s_setprio(1);
#pragma unroll
            for (int t = 0; t < 4; ++t) {
                const int rbase = (t * 16 + l16) * 64;
                s8 kv0 = *(const s8*)&KsP[rbase + coff0];
                s8 kv1 = *(const s8*)&KsP[rbase + coff1];
                s0[t] = __builtin_amdgcn_mfma_f32_16x16x32_bf16(kv0, qf00, s0[t], 0, 0, 0);
                s1[t] = __builtin_amdgcn_mfma_f32_16x16x32_bf16(kv0, qf01, s1[t], 0, 0, 0);
                s0[t] = __builtin_amdgcn_mfma_f32_16x16x32_bf16(kv1, qf10, s0[t], 0, 0, 0);
                s1[t] = __builtin_amdgcn_mfma_f32_16x16x32_bf16(kv1, qf11, s1[t], 0, 0, 0);
            }
            __builtin_amdgcn_s_setprio(0);

            if (j == jmine) {                       // diagonal tile: mask k > q
#pragma unroll
                for (int t = 0; t < 4; ++t) {
                    const int kb = j * 64 + t * 16 + quad * 4;
#pragma unroll
                    for (int r = 0; r < 4; ++r) {
                        if (kb + r > q0)      s0[t][r] = -1e30f;
                        if (kb + r > q0 + 16) s1[t][r] = -1e30f;
                    }
                }
            }

            // fixed-max softmax in exp2 domain; column sums in-reg + 2 shfl per qn
            float rs0 = 0.0f, rs1 = 0.0f;
#pragma unroll
            for (int t = 0; t < 4; ++t)
#pragma unroll
                for (int r = 0; r < 4; ++r) {
                    const float p0 = __builtin_amdgcn_exp2f(s0[t][r]);
                    const float p1 = __builtin_amdgcn_exp2f(s1[t][r]);
                    s0[t][r] = p0; rs0 += p0;
                    s1[t][r] = p1; rs1 += p1;
                }
            rs0 += __shfl_xor(rs0, 16);
            rs0 += __shfl_xor(rs0, 32);
            rs1 += __shfl_xor(rs1, 16);
            rs1 += __shfl_xor(rs1, 32);
            l0 += rs0;
            l1 += rs1;

            // pack P pairs (trunc bf16); own regs ARE the PV B-frag (k-permuted)
            union { int i[8]; s8 v[2]; } pk0, pk1;
#pragma unroll
            for (int t = 0; t < 4; ++t) {
                pk0.i[t * 2]     = pkbf(s0[t][1], s0[t][0]);
                pk0.i[t * 2 + 1] = pkbf(s0[t][3], s0[t][2]);
                pk1.i[t * 2]     = pkbf(s1[t][1], s1[t][0]);
                pk1.i[t * 2 + 1] = pkbf(s1[t][3], s1[t][2]);
            }

            // O^T[d][q] += V^T . P, two q-subtiles share each V fragment
            __builtin_amdgcn_s_setprio(1);
#pragma unroll
            for (int t = 0; t < 4; ++t) {
                const int rbase = (t * 16 + l16) * 64;
                s8 va0 = *(const s8*)&VsP[rbase + coff0];
                s8 va1 = *(const s8*)&VsP[rbase + coff1];
                o0[t] = __builtin_amdgcn_mfma_f32_16x16x32_bf16(va0, pk0.v[0], o0[t], 0, 0, 0);
                o1[t] = __builtin_amdgcn_mfma_f32_16x16x32_bf16(va0, pk1.v[0], o1[t], 0, 0, 0);
                o0[t] = __builtin_amdgcn_mfma_f32_16x16x32_bf16(va1, pk0.v[1], o0[t], 0, 0, 0);
                o1[t] = __builtin_amdgcn_mfma_f32_16x16x32_bf16(va1, pk1.v[1], o1[t], 0, 0, 0);
            }
            __builtin_amdgcn_s_setprio(0);
        }
    }

    // ---- cross-parity merge via LDS (reuse K/V buffers), then store ----
    __syncthreads();
    float* mO = (float*)&Ks[0][0][0][0];            // 4 slots x 64 lanes x 128B = 32KB
    float* mL = (float*)&Vs[0][0][0][0];
    const int slot = (wave >> 2) * 2 + qh;          // partner waves (par 0/1) share slot
    const int mrow = slot * 64 + lane;
    char* mp = (char*)mO + (size_t)mrow * 128;
    const int msw = (lane & 7) << 4;                // bank-spread XOR for merge traffic
    if (par == 1) {
#pragma unroll
        for (int t = 0; t < 4; ++t) {
            *(f4*)(mp + ((t * 32)      ^ msw)) = o0[t];
            *(f4*)(mp + ((t * 32 + 16) ^ msw)) = o1[t];
        }
        mL[mrow * 2]     = l0;
        mL[mrow * 2 + 1] = l1;
    }
    __syncthreads();
    if (par == 0) {
#pragma unroll
        for (int t = 0; t < 4; ++t) {
            o0[t] += *(const f4*)(mp + ((t * 32)      ^ msw));
            o1[t] += *(const f4*)(mp + ((t * 32 + 16) ^ msw));
        }
        l0 += mL[mrow * 2];
        l1 += mL[mrow * 2 + 1];
        const float inv0 = 1.0f / l0;
        const float inv1 = 1.0f / l1;
#pragma unroll
        for (int t = 0; t < 4; ++t) {
            us4 ov;
#pragma unroll
            for (int r = 0; r < 4; ++r) ov[r] = f2bf(o0[t][r] * inv0);
            *(us4*)&Og[(size_t)q0 * EMB + colbase + t * 16 + quad * 4] = ov;
#pragma unroll
            for (int r = 0; r < 4; ++r) ov[r] = f2bf(o1[t][r] * inv1);
            *(us4*)&Og[(size_t)(q0 + 16) * EMB + colbase + t * 16 + quad * 4] = ov;
        }
    }
}

extern "C" void kernel_launch(void* const* d_in, const int* in_sizes, int n_in,
                              void* d_out, int out_size, void* d_ws, size_t ws_size,
                              hipStream_t stream) {
    const float* x  = (const float*)d_in[0];
    const float* Wq = (const float*)d_in[1];
    const float* bq = (const float*)d_in[2];
    const float* Wk = (const float*)d_in[3];
    const float* bk = (const float*)d_in[4];
    const float* Wv = (const float*)d_in[5];
    const float* bv = (const float*)d_in[6];
    const float* Wo = (const float*)d_in[7];
    const float* bo = (const float*)d_in[8];
    float* out = (float*)d_out;

    unsigned short* ws = (unsigned short*)d_ws;
    unsigned short* xb  = ws;                          // [4096][1024]
    unsigned short* Wqb = xb  + (size_t)SEQ * EMB;     // [1024][1024] x4
    unsigned short* Wkb = Wqb + (size_t)EMB * EMB;
    unsigned short* Wvb = Wkb + (size_t)EMB * EMB;
    unsigned short* Wob = Wvb + (size_t)EMB * EMB;
    unsigned short* Qb  = Wob + (size_t)EMB * EMB;     // [4096][1024], pre-scaled 0.125*log2e
    unsigned short* Kb  = Qb  + (size_t)SEQ * EMB;     // [4096][1024]
    unsigned short* Vtb = Kb  + (size_t)SEQ * EMB;     // [1024][4096]  V^T, k-permuted cols
    unsigned short* Ab  = Vtb + (size_t)SEQ * EMB;     // attn out

    cvt_all<<<8192, 256, 0, stream>>>(x, Wq, Wk, Wv, Wo, xb, Wqb, Wkb, Wvb, Wob);

    // V region writes Vtb directly (transposed + k-permuted); no transpose kernel
    qkv_gemm<<<dim3(SEQ / 128, 24), 256, 0, stream>>>(xb, Wqb, Wkb, Wvb, bq, bk, bv, Qb, Kb, Vtb);

    attn_kernel<<<dim3(NH, 32), 512, 0, stream>>>(Qb, Kb, Vtb, Ab);

    gemm_op<<<dim3(SEQ / 128, EMB / 64), 256, 0, stream>>>(Ab, Wob, bo, out);
}